// Round 1
// baseline (313.185 us; speedup 1.0000x reference)
//
#include <hip/hip_runtime.h>

#define BATCH 16384
#define DIM 64

// One row per 16-lane group: each lane loads a float4 (16 lanes * 4 = 64 elems)
// from both gathered rows, computes partial dot + partial sum-of-squares,
// shfl-reduces within the group, leader applies loss, block reduces, one
// atomicAdd per block.
__global__ __launch_bounds__(256)
void pmf_kernel(const int* __restrict__ u, const int* __restrict__ iidx,
                const int* __restrict__ s, const float* __restrict__ W,
                const float* __restrict__ H, float* __restrict__ out)
{
    const int tid = threadIdx.x;
    const int row = blockIdx.x * 16 + (tid >> 4);   // grid exactly covers BATCH
    const int l16 = tid & 15;

    const int uu = u[row];
    const int ii = iidx[row];
    const int srow = s[row];

    const float4 wv = reinterpret_cast<const float4*>(W + (size_t)uu * DIM)[l16];
    const float4 hv = reinterpret_cast<const float4*>(H + (size_t)ii * DIM)[l16];

    float dot = wv.x * hv.x + wv.y * hv.y + wv.z * hv.z + wv.w * hv.w;
    float reg = 0.01f * (wv.x * wv.x + wv.y * wv.y + wv.z * wv.z + wv.w * wv.w)
              + 0.01f * (hv.x * hv.x + hv.y * hv.y + hv.z * hv.z + hv.w * hv.w);

    // reduce dot/reg across the 16-lane group
    #pragma unroll
    for (int off = 8; off > 0; off >>= 1) {
        dot += __shfl_down(dot, off, 16);
        reg += __shfl_down(reg, off, 16);
    }

    float contrib = 0.0f;
    if (l16 == 0) {
        const float x = dot;
        // numerically stable log_sigmoid
        const float ls = fminf(x, 0.0f) - log1pf(expf(-fabsf(x)));
        const float t = (float)srow - ls;
        contrib = (t * t + reg) * (1.0f / (float)BATCH);
    }

    // reduce contrib across the full 64-lane wave (non-leaders hold 0)
    #pragma unroll
    for (int off = 32; off > 0; off >>= 1)
        contrib += __shfl_down(contrib, off, 64);

    __shared__ float wave_sums[4];
    if ((tid & 63) == 0) wave_sums[tid >> 6] = contrib;
    __syncthreads();

    if (tid == 0) {
        const float blk = wave_sums[0] + wave_sums[1] + wave_sums[2] + wave_sums[3];
        atomicAdd(out, blk);
    }
}

extern "C" void kernel_launch(void* const* d_in, const int* in_sizes, int n_in,
                              void* d_out, int out_size, void* d_ws, size_t ws_size,
                              hipStream_t stream) {
    const int*   u = (const int*)d_in[0];
    const int*   i = (const int*)d_in[1];
    const int*   s = (const int*)d_in[2];
    const float* W = (const float*)d_in[3];
    const float* H = (const float*)d_in[4];
    float* out = (float*)d_out;

    // d_out is poisoned to 0xAA before every timed launch; zero it on-stream.
    hipMemsetAsync(out, 0, sizeof(float) * (size_t)out_size, stream);

    pmf_kernel<<<BATCH / 16, 256, 0, stream>>>(u, i, s, W, H, out);
}

// Round 2
// 302.630 us; speedup vs baseline: 1.0349x; 1.0349x over previous
//
#include <hip/hip_runtime.h>

#define BATCH 16384
#define DIM 64
#define NBLOCKS 1024   // BATCH / 16 rows per block

// Kernel 1: one row per 16-lane group; each lane loads a float4 from each
// gathered row, computes partial dot + regularization, shfl-reduces within
// the group, then wave + LDS reduction -> ONE plain store per block into ws.
// No atomics, no zero-init required (we overwrite the poisoned ws).
__global__ __launch_bounds__(256)
void pmf_partial(const int* __restrict__ u, const int* __restrict__ iidx,
                 const int* __restrict__ s, const float* __restrict__ W,
                 const float* __restrict__ H, float* __restrict__ ws)
{
    const int tid = threadIdx.x;
    const int row = blockIdx.x * 16 + (tid >> 4);
    const int l16 = tid & 15;

    const int uu = u[row];
    const int ii = iidx[row];
    const int srow = s[row];

    const float4 wv = reinterpret_cast<const float4*>(W + (size_t)uu * DIM)[l16];
    const float4 hv = reinterpret_cast<const float4*>(H + (size_t)ii * DIM)[l16];

    float dot = wv.x * hv.x + wv.y * hv.y + wv.z * hv.z + wv.w * hv.w;
    float reg = 0.01f * (wv.x * wv.x + wv.y * wv.y + wv.z * wv.z + wv.w * wv.w)
              + 0.01f * (hv.x * hv.x + hv.y * hv.y + hv.z * hv.z + hv.w * hv.w);

    #pragma unroll
    for (int off = 8; off > 0; off >>= 1) {
        dot += __shfl_down(dot, off, 16);
        reg += __shfl_down(reg, off, 16);
    }

    float contrib = 0.0f;
    if (l16 == 0) {
        const float x = dot;
        const float ls = fminf(x, 0.0f) - log1pf(expf(-fabsf(x)));  // stable log_sigmoid
        const float t = (float)srow - ls;
        contrib = (t * t + reg) * (1.0f / (float)BATCH);
    }

    #pragma unroll
    for (int off = 32; off > 0; off >>= 1)
        contrib += __shfl_down(contrib, off, 64);

    __shared__ float wave_sums[4];
    if ((tid & 63) == 0) wave_sums[tid >> 6] = contrib;
    __syncthreads();

    if (tid == 0)
        ws[blockIdx.x] = wave_sums[0] + wave_sums[1] + wave_sums[2] + wave_sums[3];
}

// Kernel 2: one block reduces the 1024 partials, plain store to out[0]
// (overwrites the 0xAA poison -- no memset needed).
__global__ __launch_bounds__(256)
void pmf_final(const float* __restrict__ ws, float* __restrict__ out)
{
    const int tid = threadIdx.x;
    const float4 v = reinterpret_cast<const float4*>(ws)[tid];  // 256*4 = 1024
    float sum = v.x + v.y + v.z + v.w;

    #pragma unroll
    for (int off = 32; off > 0; off >>= 1)
        sum += __shfl_down(sum, off, 64);

    __shared__ float wave_sums[4];
    if ((tid & 63) == 0) wave_sums[tid >> 6] = sum;
    __syncthreads();

    if (tid == 0)
        out[0] = wave_sums[0] + wave_sums[1] + wave_sums[2] + wave_sums[3];
}

extern "C" void kernel_launch(void* const* d_in, const int* in_sizes, int n_in,
                              void* d_out, int out_size, void* d_ws, size_t ws_size,
                              hipStream_t stream) {
    const int*   u = (const int*)d_in[0];
    const int*   i = (const int*)d_in[1];
    const int*   s = (const int*)d_in[2];
    const float* W = (const float*)d_in[3];
    const float* H = (const float*)d_in[4];
    float* ws  = (float*)d_ws;
    float* out = (float*)d_out;

    pmf_partial<<<NBLOCKS, 256, 0, stream>>>(u, i, s, W, H, ws);
    pmf_final<<<1, 256, 0, stream>>>(ws, out);
}